// Round 13
// baseline (137.148 us; speedup 1.0000x reference)
//
#include <hip/hip_runtime.h>
#include <math.h>

#ifndef M_PI
#define M_PI 3.14159265358979323846
#endif

namespace {
constexpr int B_ = 4;
constexpr int L_ = 2048;
constexpr int D_ = 64;
constexpr int H_ = 4;
constexpr int RB = 8;           // rows per block
constexpr int KT = 64;          // K-tile
constexpr int NTILE = L_ / KT;  // 32
constexpr int CAPC = 256;       // per-wave candidate capacity
constexpr int OUTW = D_ + H_ * D_;  // 320
constexpr int APS = 2064;       // A plane stride bytes (64*16*2 + 16 pad)
}

typedef __attribute__((ext_vector_type(8))) short bf16x8;
typedef __attribute__((ext_vector_type(4))) float f32x4;

__device__ __forceinline__ unsigned bf16_rne(float x) {
    unsigned u = __float_as_uint(x);
    return (u + 0x7fffu + ((u >> 16) & 1u)) >> 16;
}

// wait lgkmcnt(0) only (vmcnt=63, expcnt=7): gfx9 imm = (vm_hi<<14)|(lgkm<<8)|(exp<<4)|vm_lo
#define LDS_FENCE() __builtin_amdgcn_s_waitcnt(0xC07F)

// ---- prep: inputs (B,L,D) fp32 -> ws bf16 k-major chunks.
// chunk g = (k>>3)*64 + n per batch; byte g*16 + (k&7)*2 holds bf16(x[k][n]).
__global__ __launch_bounds__(256) void prep_kernel(const float* __restrict__ inputs,
                                                   char* __restrict__ ws) {
    const int blk = blockIdx.x;          // 256 blocks
    const int b = blk >> 6;
    const int r6 = blk & 63;
    const int tile = r6 >> 2;            // tile of 128 k
    const int qr = r6 & 3;
    const int t = threadIdx.x;
    const float* inb = inputs + ((size_t)b * L_ + tile * 128) * D_;
    char* wsb = ws + (size_t)b * (L_ * D_ * 2) + tile * (128 * D_ * 2);
    #pragma unroll
    for (int i = 0; i < 4; ++i) {
        const int idx = qr * 1024 + i * 256 + t;   // over kp(64) x n(64)
        const int n  = idx & 63;
        const int kp = idx >> 6;
        const int kl = kp << 1;                    // even k within tile128
        const float x0 = inb[kl * D_ + n];
        const float x1 = inb[(kl + 1) * D_ + n];
        const unsigned a = bf16_rne(x0);
        const unsigned c = bf16_rne(x1);
        const int chunk = (kl >> 3) * 64 + n;
        const int e = kl & 7;
        *reinterpret_cast<unsigned*>(wsb + chunk * 16 + e * 2) = a | (c << 16);
    }
}

__global__ __launch_bounds__(512, 8) void posatt_kernel(
    const float* __restrict__ mesh,     // (B,L,2)
    const float* __restrict__ inputs,   // (B,L,D)
    const float* __restrict__ lmda,     // (H)
    const char* __restrict__ ws,        // bf16 chunk-major inputs
    float* __restrict__ out)            // (B,L,320)
{
    // time-shared: phase1 hist(8K)+cand(8K) | phase2 A(2*2064)+B(8192) | epilogue C(8K)
    __shared__ __align__(16) char s_u1[16448];
    __shared__ float s_scale[H_];
    __shared__ float s_th[RB][H_];
    __shared__ float s_d409[RB], s_d410[RB];
    __shared__ float s_wsum[RB][H_];
    __shared__ unsigned s_ccw[8];

    const int t = threadIdx.x;
    const int l = t & 63;
    const int w = t >> 6;               // 8 waves
    const int blk = blockIdx.x;         // 1024
    const int b = blk >> 8;
    const int n0 = (blk & 255) * RB;

    const float2* meshg = reinterpret_cast<const float2*>(mesh) + (size_t)b * L_;

    // per-head scale (exact, verified R2 path)
    if (t < H_) {
        const double lam = (double)lmda[t];
        const float C = (float)(0.25 * M_PI * (1.0 - 1e-07));
        const float s1 = (float)sin(lam);
        const float arg = __fmul_rn(C, __fadd_rn(1.0f, s1));
        s_scale[t] = (float)tan((double)arg);
    }
    __syncthreads();

    // ---- phase 1: per-wave exact rank-409/410 select; mesh from global (L1/L2)
    {
        unsigned* hw = reinterpret_cast<unsigned*>(s_u1) + w * 256;          // 1 KB/wave
        float* cw = reinterpret_cast<float*>(s_u1 + 8192) + w * CAPC;        // 1 KB/wave
        const int rl = w;
        const float2 me = meshg[n0 + rl];
        *reinterpret_cast<uint4*>(&hw[l * 4]) = make_uint4(0u, 0u, 0u, 0u);
        if (l == 0) s_ccw[w] = 0u;
        LDS_FENCE();
        #pragma unroll 4
        for (int it = 0; it < 32; ++it) {
            const int j = (it << 6) + l;
            const float2 mj = meshg[j];
            const float dx = __fsub_rn(me.x, mj.x);
            const float dy = __fsub_rn(me.y, mj.y);
            const float d = __fadd_rn(__fmul_rn(dx, dx), __fmul_rn(dy, dy));
            int bin = (int)(d * 128.0f); bin = bin < 255 ? bin : 255;
            atomicAdd(&hw[bin], 1u);
        }
        LDS_FENCE();
        // level-1 scan + crossings at ranks 409/410
        int lo, hi; unsigned base;
        {
            const uint4 hv = *reinterpret_cast<const uint4*>(&hw[l * 4]);
            const unsigned p0 = hv.x, p1 = p0 + hv.y, p2 = p1 + hv.z, p3 = p2 + hv.w;
            unsigned sc = p3;
            #pragma unroll
            for (int off = 1; off < 64; off <<= 1) {
                const unsigned uu = __shfl_up(sc, off);
                if (l >= off) sc += uu;
            }
            const unsigned eb = sc - p3;
            const unsigned cum[4] = {eb + p0, eb + p1, eb + p2, eb + p3};
            int flo = -1, fhi = -1; unsigned fbase = 0u;
            #pragma unroll
            for (int e = 0; e < 4; ++e) {
                const unsigned prev = e ? cum[e - 1] : eb;
                if (cum[e] > 409u && prev <= 409u) { flo = l * 4 + e; fbase = prev; }
                if (cum[e] > 410u && prev <= 410u) { fhi = l * 4 + e; }
            }
            const unsigned long long bmlo = __ballot(flo >= 0);
            const int srclo = (int)__builtin_ctzll(bmlo);
            lo = __shfl(flo, srclo);
            base = __shfl(fbase, srclo);
            const unsigned long long bmhi = __ballot(fhi >= 0);
            hi = __shfl(fhi, (int)__builtin_ctzll(bmhi));
        }
        // gather candidates from bins [lo,hi] (recompute d; global mesh)
        #pragma unroll 4
        for (int it = 0; it < 32; ++it) {
            const int j = (it << 6) + l;
            const float2 mj = meshg[j];
            const float dx = __fsub_rn(me.x, mj.x);
            const float dy = __fsub_rn(me.y, mj.y);
            const float d = __fadd_rn(__fmul_rn(dx, dx), __fmul_rn(dy, dy));
            int bin = (int)(d * 128.0f); bin = bin < 255 ? bin : 255;
            if (bin >= lo && bin <= hi) {
                const unsigned p = atomicAdd(&s_ccw[w], 1u);
                if (p < (unsigned)CAPC) cw[p] = d;
            }
        }
        LDS_FENCE();
        const int m = (int)min(s_ccw[w], (unsigned)CAPC);
        const unsigned k409 = 409u - base;      // rank within cw
        const unsigned k410 = 410u - base;
        // ---- level-2 refine: 256 sub-bins over the candidate value range (monotone map)
        const float lo_edge = (float)lo * 0.0078125f;          // lo/128, exact
        const float sc2 = 32768.0f / (float)(hi - lo + 1);     // 256*128/(span bins)
        *reinterpret_cast<uint4*>(&hw[l * 4]) = make_uint4(0u, 0u, 0u, 0u);
        LDS_FENCE();
        #pragma unroll 2
        for (int ci = l; ci < m; ci += 64) {
            const float v = cw[ci];
            int b2 = (int)(__fmul_rn(__fsub_rn(v, lo_edge), sc2));
            b2 = b2 < 255 ? b2 : 255; b2 = b2 > 0 ? b2 : 0;
            atomicAdd(&hw[b2], 1u);
        }
        LDS_FENCE();
        // level-2 scan + crossings at ranks k409/k410
        int lo2, hi2; unsigned base2;
        {
            const uint4 hv = *reinterpret_cast<const uint4*>(&hw[l * 4]);
            const unsigned p0 = hv.x, p1 = p0 + hv.y, p2 = p1 + hv.z, p3 = p2 + hv.w;
            unsigned sc = p3;
            #pragma unroll
            for (int off = 1; off < 64; off <<= 1) {
                const unsigned uu = __shfl_up(sc, off);
                if (l >= off) sc += uu;
            }
            const unsigned eb = sc - p3;
            const unsigned cum[4] = {eb + p0, eb + p1, eb + p2, eb + p3};
            int flo = -1, fhi = -1; unsigned fbase = 0u;
            #pragma unroll
            for (int e = 0; e < 4; ++e) {
                const unsigned prev = e ? cum[e - 1] : eb;
                if (cum[e] > k409 && prev <= k409) { flo = l * 4 + e; fbase = prev; }
                if (cum[e] > k410 && prev <= k410) { fhi = l * 4 + e; }
            }
            const unsigned long long bmlo = __ballot(flo >= 0);
            const int srclo = (int)__builtin_ctzll(bmlo);
            lo2 = __shfl(flo, srclo);
            base2 = __shfl(fbase, srclo);
            const unsigned long long bmhi = __ballot(fhi >= 0);
            hi2 = __shfl(fhi, (int)__builtin_ctzll(bmhi));
        }
        // gather level-2 candidates into the (now dead) hist region
        if (l == 0) s_ccw[w] = 0u;
        LDS_FENCE();
        float* c2 = reinterpret_cast<float*>(hw);   // 256 slots
        #pragma unroll 2
        for (int ci = l; ci < m; ci += 64) {
            const float v = cw[ci];
            int b2 = (int)(__fmul_rn(__fsub_rn(v, lo_edge), sc2));
            b2 = b2 < 255 ? b2 : 255; b2 = b2 > 0 ? b2 : 0;
            if (b2 >= lo2 && b2 <= hi2) {
                const unsigned p = atomicAdd(&s_ccw[w], 1u);
                if (p < 256u) c2[p] = v;
            }
        }
        LDS_FENCE();
        const int c = (int)min(s_ccw[w], 256u);
        const int q409 = (int)(k409 - base2);
        const int q410 = (int)(k410 - base2);
        #pragma unroll 1
        for (int cc0 = 0; cc0 < c; cc0 += 64) {
            const int ci = cc0 + l;
            const float v = (ci < c) ? c2[ci] : 0.0f;
            int lt = 0, le = 0;
            #pragma unroll 4
            for (int i = 0; i < c; ++i) {
                const float u = c2[i];
                lt += (u < v) ? 1 : 0;
                le += (u <= v) ? 1 : 0;
            }
            if (ci < c) {
                if (lt <= q409 && q409 < le) s_d409[rl] = v;
                if (lt <= q410 && q410 < le) s_d410[rl] = v;
            }
        }
    }
    __syncthreads();

    // thresholds (exact jnp.quantile lerp, verified R2 path)
    if (t < RB * H_) {
        const int r = t >> 2, h = t & 3;
        const float scl = s_scale[h];
        const float s409 = __fmul_rn(s_d409[r], scl);
        const float s410 = __fmul_rn(s_d410[r], scl);
        const float pos = 0.2f * 2047.0f;
        const float g = pos - 409.0f;
        const float lw = 1.0f - g;
        s_th[r][h] = __fadd_rn(__fmul_rn(s409, lw), __fmul_rn(s410, g));
    }
    __syncthreads();

    // ---- phase 2: K-tiled (KT=64) bf16 A-build + MFMA; mesh from global (R10-verified math)
    const int mr   = t >> 4;
    const int h_b  = mr >> 3;
    const int r_b  = mr & 7;
    const int jg   = t & 15;
    const int row16 = ((h_b & 1) << 3) + r_b;
    const int pln   = h_b >> 1;
    const float2 me_b = meshg[n0 + r_b];
    const float sc_b = s_scale[h_b];
    const float th_b = s_th[r_b][h_b];
    // A write offset with XOR bank swizzle: chunkSw = chunk ^ (ks4q & 7)
    const int ks4q_w = jg >> 1;
    const int chunk_w = ks4q_w * 16 + row16;
    const int chunkSw_w = chunk_w ^ (ks4q_w & 7);
    const int aoff = pln * APS + (chunkSw_w << 4) + ((jg & 1) << 3);
    float wacc = 0.0f;

    // MFMA roles: plane p_w, k-step ks_w, col-half nqh
    const int p_w  = w >> 2;
    const int ks_w = (w >> 1) & 1;
    const int nqh  = w & 1;
    // swizzled A-read offset for this lane
    const int ks4q_r = ks_w * 4 + (l >> 4);
    const int chunk_r = ks4q_r * 16 + (l & 15);
    const int aroff = p_w * APS + ((chunk_r ^ (ks4q_r & 7)) << 4);
    f32x4 acc[2];
    acc[0] = (f32x4)0.0f; acc[1] = (f32x4)0.0f;

    const float* inpb = inputs + (size_t)b * L_ * D_;
    const char* wsb = ws + (size_t)b * (L_ * D_ * 2);
    char* Abase = s_u1;                 // 2 planes x APS = 4128 B
    char* Bbase = s_u1 + 2 * APS;       // 8192 B

    #pragma unroll 1
    for (int tile = 0; tile < NTILE; ++tile) {
        __syncthreads();
        // B stage: pre-converted bf16 chunk from ws (1 uint4 per thread)
        const uint4 bg = *reinterpret_cast<const uint4*>(wsb + ((size_t)(tile * 512 + t) << 4));
        // A-build: 4 consecutive j per thread; mesh points from global
        const int k0 = tile * KT;
        {
            const float4 mq0 = *reinterpret_cast<const float4*>(&meshg[k0 + jg * 4]);
            const float4 mq1 = *reinterpret_cast<const float4*>(&meshg[k0 + jg * 4 + 2]);
            const float dx0 = __fsub_rn(me_b.x, mq0.x);
            const float dy0 = __fsub_rn(me_b.y, mq0.y);
            const float d0 = __fadd_rn(__fmul_rn(dx0, dx0), __fmul_rn(dy0, dy0));
            const float dx1 = __fsub_rn(me_b.x, mq0.z);
            const float dy1 = __fsub_rn(me_b.y, mq0.w);
            const float d1 = __fadd_rn(__fmul_rn(dx1, dx1), __fmul_rn(dy1, dy1));
            const float dx2 = __fsub_rn(me_b.x, mq1.x);
            const float dy2 = __fsub_rn(me_b.y, mq1.y);
            const float d2 = __fadd_rn(__fmul_rn(dx2, dx2), __fmul_rn(dy2, dy2));
            const float dx3 = __fsub_rn(me_b.x, mq1.z);
            const float dy3 = __fsub_rn(me_b.y, mq1.w);
            const float d3 = __fadd_rn(__fmul_rn(dx3, dx3), __fmul_rn(dy3, dy3));
            const float x0 = __fmul_rn(d0, sc_b);
            const float x1 = __fmul_rn(d1, sc_b);
            const float x2 = __fmul_rn(d2, sc_b);
            const float x3 = __fmul_rn(d3, sc_b);
            const float w0 = (x0 <= th_b) ? __expf(-x0) : 0.0f;
            const float w1 = (x1 <= th_b) ? __expf(-x1) : 0.0f;
            const float w2 = (x2 <= th_b) ? __expf(-x2) : 0.0f;
            const float w3 = (x3 <= th_b) ? __expf(-x3) : 0.0f;
            wacc += (w0 + w1) + (w2 + w3);
            const unsigned u01 = bf16_rne(w0) | (bf16_rne(w1) << 16);
            const unsigned u23 = bf16_rne(w2) | (bf16_rne(w3) << 16);
            *reinterpret_cast<uint2*>(Abase + aoff) = make_uint2(u01, u23);
        }
        // commit B to LDS
        *reinterpret_cast<uint4*>(Bbase + t * 16) = bg;
        __syncthreads();
        // MFMA: wave handles plane p_w, k-step ks_w, col-quads nqh*2, nqh*2+1
        const bf16x8 afr = *reinterpret_cast<const bf16x8*>(Abase + aroff);
        #pragma unroll
        for (int i = 0; i < 2; ++i) {
            const int nq = nqh * 2 + i;
            const bf16x8 bfr = *reinterpret_cast<const bf16x8*>(
                Bbase + (((ks_w * 4 + (l >> 4)) * 64 + nq * 16 + (l & 15)) << 4));
            acc[i] = __builtin_amdgcn_mfma_f32_16x16x32_bf16(afr, bfr, acc[i], 0, 0, 0);
        }
    }
    __syncthreads();

    // wsum: reduce over jg lanes, unique writer
    wacc += __shfl_xor(wacc, 1);
    wacc += __shfl_xor(wacc, 2);
    wacc += __shfl_xor(wacc, 4);
    wacc += __shfl_xor(wacc, 8);
    if ((l & 15) == 0) s_wsum[r_b][h_b] = wacc;
    // zero C region (8 KB)
    {
        float4* Cz = reinterpret_cast<float4*>(s_u1);
        Cz[t] = make_float4(0.f, 0.f, 0.f, 0.f);
    }
    __syncthreads();
    // reduce k-split accumulator frags into C[32][64]
    {
        float* Cf = reinterpret_cast<float*>(s_u1);
        #pragma unroll
        for (int i = 0; i < 2; ++i) {
            const int nq = nqh * 2 + i;
            #pragma unroll
            for (int reg = 0; reg < 4; ++reg) {
                const int row = (l >> 4) * 4 + reg;
                const int col = nq * 16 + (l & 15);
                atomicAdd(&Cf[(p_w * 16 + row) * 64 + col], acc[i][reg]);
            }
        }
    }
    __syncthreads();
    // normalize + store conv block
    {
        const float* Cf = reinterpret_cast<const float*>(s_u1);
        const int pr = t >> 4;                  // 0..31
        const int p = pr >> 4;
        const int row16o = pr & 15;
        const int h = p * 2 + (row16o >> 3);
        const int r = row16o & 7;
        const int col = (t & 15) << 2;
        const float wsv = s_wsum[r][h];
        const float inv = (wsv != 0.0f) ? 1.0f / wsv : 0.0f;
        float4 r0 = *reinterpret_cast<const float4*>(&Cf[pr * 64 + col]);
        r0.x *= inv; r0.y *= inv; r0.z *= inv; r0.w *= inv;
        float* op = out + (size_t)(b * L_ + n0 + r) * OUTW + D_ + h * 64 + col;
        *reinterpret_cast<float4*>(op) = r0;
    }
    // exact fp32 passthrough of inputs into out[:, :, 0:64]
    {
        const int r = t >> 6;                   // 0..7
        const int c = t & 63;
        out[(size_t)(b * L_ + n0 + r) * OUTW + c] = inpb[(size_t)(n0 + r) * D_ + c];
    }
}

extern "C" void kernel_launch(void* const* d_in, const int* in_sizes, int n_in,
                              void* d_out, int out_size, void* d_ws, size_t ws_size,
                              hipStream_t stream) {
    const float* mesh   = (const float*)d_in[0];
    const float* inputs = (const float*)d_in[1];
    const float* lmda   = (const float*)d_in[2];
    float* out = (float*)d_out;
    char* ws = (char*)d_ws;
    (void)in_sizes; (void)n_in; (void)out_size; (void)ws_size;
    hipLaunchKernelGGL(prep_kernel, dim3(256), dim3(256), 0, stream, inputs, ws);
    hipLaunchKernelGGL(posatt_kernel, dim3(B_ * (L_ / RB)), dim3(512), 0, stream,
                       mesh, inputs, lmda, ws, out);
}

// Round 15
// 132.726 us; speedup vs baseline: 1.0333x; 1.0333x over previous
//
#include <hip/hip_runtime.h>
#include <math.h>

#ifndef M_PI
#define M_PI 3.14159265358979323846
#endif

namespace {
constexpr int B_ = 4;
constexpr int L_ = 2048;
constexpr int D_ = 64;
constexpr int H_ = 4;
constexpr int RB = 8;           // rows per block
constexpr int KT = 64;          // K-tile
constexpr int NTILE = L_ / KT;  // 32
constexpr int CAPC = 256;       // per-wave candidate capacity
constexpr int OUTW = D_ + H_ * D_;  // 320
constexpr int APS = 2064;       // A plane stride bytes (64*16*2 + 16 pad)
}

typedef __attribute__((ext_vector_type(8))) short bf16x8;
typedef __attribute__((ext_vector_type(4))) float f32x4;

__device__ __forceinline__ unsigned bf16_rne(float x) {
    unsigned u = __float_as_uint(x);
    return (u + 0x7fffu + ((u >> 16) & 1u)) >> 16;
}

// wait lgkmcnt(0) only (vmcnt=63, expcnt=7)
#define LDS_FENCE() __builtin_amdgcn_s_waitcnt(0xC07F)

// ---- prep: inputs (B,L,D) fp32 -> ws bf16 k-major chunks.
__global__ __launch_bounds__(256) void prep_kernel(const float* __restrict__ inputs,
                                                   char* __restrict__ ws) {
    const int blk = blockIdx.x;          // 256 blocks
    const int b = blk >> 6;
    const int r6 = blk & 63;
    const int tile = r6 >> 2;            // tile of 128 k
    const int qr = r6 & 3;
    const int t = threadIdx.x;
    const float* inb = inputs + ((size_t)b * L_ + tile * 128) * D_;
    char* wsb = ws + (size_t)b * (L_ * D_ * 2) + tile * (128 * D_ * 2);
    #pragma unroll
    for (int i = 0; i < 4; ++i) {
        const int idx = qr * 1024 + i * 256 + t;   // over kp(64) x n(64)
        const int n  = idx & 63;
        const int kp = idx >> 6;
        const int kl = kp << 1;                    // even k within tile128
        const float x0 = inb[kl * D_ + n];
        const float x1 = inb[(kl + 1) * D_ + n];
        const unsigned a = bf16_rne(x0);
        const unsigned c = bf16_rne(x1);
        const int chunk = (kl >> 3) * 64 + n;
        const int e = kl & 7;
        *reinterpret_cast<unsigned*>(wsb + chunk * 16 + e * 2) = a | (c << 16);
    }
}

__global__ __launch_bounds__(512, 8) void posatt_kernel(
    const float* __restrict__ mesh,     // (B,L,2)
    const float* __restrict__ inputs,   // (B,L,D)
    const float* __restrict__ lmda,     // (H)
    const char* __restrict__ ws,        // bf16 chunk-major inputs
    float* __restrict__ out)            // (B,L,320)
{
    __shared__ __align__(16) float2 s_mesh[L_];       // 16 KB (phase 2)
    // time-shared: phase1 hist(8K)+cand(8K) | phase2 A(2*2064)+B(8192) | epilogue C(8K)
    __shared__ __align__(16) char s_u1[16448];
    __shared__ float s_scale[H_];
    __shared__ float s_th[RB][H_];
    __shared__ float s_d409[RB], s_d410[RB];
    __shared__ float s_wsum[RB][H_];
    __shared__ unsigned s_ccw[8];

    const int t = threadIdx.x;
    const int l = t & 63;
    const int w = t >> 6;               // 8 waves
    const int blk = blockIdx.x;         // 1024
    const int b = blk >> 8;
    const int n0 = (blk & 255) * RB;

    const float2* meshg = reinterpret_cast<const float2*>(mesh) + (size_t)b * L_;

    // per-head scale (exact, verified R2 path)
    if (t < H_) {
        const double lam = (double)lmda[t];
        const float C = (float)(0.25 * M_PI * (1.0 - 1e-07));
        const float s1 = (float)sin(lam);
        const float arg = __fmul_rn(C, __fadd_rn(1.0f, s1));
        s_scale[t] = (float)tan((double)arg);
    }
    if (t < RB) { s_d409[t] = 0.0f; s_d410[t] = 0.0f; }   // deterministic fallback
    // stage mesh (for phase 2)
    {
        const float4* mg = reinterpret_cast<const float4*>(mesh + (size_t)b * L_ * 2);
        float4* msd = reinterpret_cast<float4*>(s_mesh);
        msd[t] = mg[t];
        msd[t + 512] = mg[t + 512];
    }
    __syncthreads();

    // ---- phase 1 (R13-verified verbatim): rank-409/410 select; mesh from global
    {
        unsigned* hw = reinterpret_cast<unsigned*>(s_u1) + w * 256;          // 1 KB/wave
        float* cw = reinterpret_cast<float*>(s_u1 + 8192) + w * CAPC;        // 1 KB/wave
        const int rl = w;
        const float2 me = meshg[n0 + rl];
        *reinterpret_cast<uint4*>(&hw[l * 4]) = make_uint4(0u, 0u, 0u, 0u);
        if (l == 0) s_ccw[w] = 0u;
        LDS_FENCE();
        #pragma unroll 4
        for (int it = 0; it < 32; ++it) {
            const int j = (it << 6) + l;
            const float2 mj = meshg[j];
            const float dx = __fsub_rn(me.x, mj.x);
            const float dy = __fsub_rn(me.y, mj.y);
            const float d = __fadd_rn(__fmul_rn(dx, dx), __fmul_rn(dy, dy));
            int bin = (int)(d * 128.0f); bin = bin < 255 ? bin : 255;
            atomicAdd(&hw[bin], 1u);
        }
        LDS_FENCE();
        // level-1 scan + crossings at ranks 409/410
        int lo, hi; unsigned base;
        {
            const uint4 hv = *reinterpret_cast<const uint4*>(&hw[l * 4]);
            const unsigned p0 = hv.x, p1 = p0 + hv.y, p2 = p1 + hv.z, p3 = p2 + hv.w;
            unsigned sc = p3;
            #pragma unroll
            for (int off = 1; off < 64; off <<= 1) {
                const unsigned uu = __shfl_up(sc, off);
                if (l >= off) sc += uu;
            }
            const unsigned eb = sc - p3;
            const unsigned cum[4] = {eb + p0, eb + p1, eb + p2, eb + p3};
            int flo = -1, fhi = -1; unsigned fbase = 0u;
            #pragma unroll
            for (int e = 0; e < 4; ++e) {
                const unsigned prev = e ? cum[e - 1] : eb;
                if (cum[e] > 409u && prev <= 409u) { flo = l * 4 + e; fbase = prev; }
                if (cum[e] > 410u && prev <= 410u) { fhi = l * 4 + e; }
            }
            const unsigned long long bmlo = __ballot(flo >= 0);
            const int srclo = (int)__builtin_ctzll(bmlo);
            lo = __shfl(flo, srclo);
            base = __shfl(fbase, srclo);
            const unsigned long long bmhi = __ballot(fhi >= 0);
            hi = __shfl(fhi, (int)__builtin_ctzll(bmhi));
        }
        // gather candidates from bins [lo,hi] (recompute d; global mesh)
        #pragma unroll 4
        for (int it = 0; it < 32; ++it) {
            const int j = (it << 6) + l;
            const float2 mj = meshg[j];
            const float dx = __fsub_rn(me.x, mj.x);
            const float dy = __fsub_rn(me.y, mj.y);
            const float d = __fadd_rn(__fmul_rn(dx, dx), __fmul_rn(dy, dy));
            int bin = (int)(d * 128.0f); bin = bin < 255 ? bin : 255;
            if (bin >= lo && bin <= hi) {
                const unsigned p = atomicAdd(&s_ccw[w], 1u);
                if (p < (unsigned)CAPC) cw[p] = d;
            }
        }
        LDS_FENCE();
        const int m = (int)min(s_ccw[w], (unsigned)CAPC);
        const unsigned k409 = 409u - base;      // rank within cw
        const unsigned k410 = 410u - base;
        // ---- level-2 refine: 256 sub-bins over candidate range (R13-verified)
        const float lo_edge = (float)lo * 0.0078125f;          // lo/128, exact
        const float sc2 = 32768.0f / (float)(hi - lo + 1);     // 256*128/(span bins)
        *reinterpret_cast<uint4*>(&hw[l * 4]) = make_uint4(0u, 0u, 0u, 0u);
        LDS_FENCE();
        #pragma unroll 2
        for (int ci = l; ci < m; ci += 64) {
            const float v = cw[ci];
            int b2 = (int)(__fmul_rn(__fsub_rn(v, lo_edge), sc2));
            b2 = b2 < 255 ? b2 : 255; b2 = b2 > 0 ? b2 : 0;
            atomicAdd(&hw[b2], 1u);
        }
        LDS_FENCE();
        int lo2, hi2; unsigned base2;
        {
            const uint4 hv = *reinterpret_cast<const uint4*>(&hw[l * 4]);
            const unsigned p0 = hv.x, p1 = p0 + hv.y, p2 = p1 + hv.z, p3 = p2 + hv.w;
            unsigned sc = p3;
            #pragma unroll
            for (int off = 1; off < 64; off <<= 1) {
                const unsigned uu = __shfl_up(sc, off);
                if (l >= off) sc += uu;
            }
            const unsigned eb = sc - p3;
            const unsigned cum[4] = {eb + p0, eb + p1, eb + p2, eb + p3};
            int flo = -1, fhi = -1; unsigned fbase = 0u;
            #pragma unroll
            for (int e = 0; e < 4; ++e) {
                const unsigned prev = e ? cum[e - 1] : eb;
                if (cum[e] > k409 && prev <= k409) { flo = l * 4 + e; fbase = prev; }
                if (cum[e] > k410 && prev <= k410) { fhi = l * 4 + e; }
            }
            const unsigned long long bmlo = __ballot(flo >= 0);
            const int srclo = (int)__builtin_ctzll(bmlo);
            lo2 = __shfl(flo, srclo);
            base2 = __shfl(fbase, srclo);
            const unsigned long long bmhi = __ballot(fhi >= 0);
            hi2 = __shfl(fhi, (int)__builtin_ctzll(bmhi));
        }
        if (l == 0) s_ccw[w] = 0u;
        LDS_FENCE();
        float* c2 = reinterpret_cast<float*>(hw);   // 256 slots (dead hist)
        #pragma unroll 2
        for (int ci = l; ci < m; ci += 64) {
            const float v = cw[ci];
            int b2 = (int)(__fmul_rn(__fsub_rn(v, lo_edge), sc2));
            b2 = b2 < 255 ? b2 : 255; b2 = b2 > 0 ? b2 : 0;
            if (b2 >= lo2 && b2 <= hi2) {
                const unsigned p = atomicAdd(&s_ccw[w], 1u);
                if (p < 256u) c2[p] = v;
            }
        }
        LDS_FENCE();
        const int c = (int)min(s_ccw[w], 256u);
        const int q409 = (int)(k409 - base2);
        const int q410 = (int)(k410 - base2);
        #pragma unroll 1
        for (int cc0 = 0; cc0 < c; cc0 += 64) {
            const int ci = cc0 + l;
            const float v = (ci < c) ? c2[ci] : 0.0f;
            int lt = 0, le = 0;
            #pragma unroll 4
            for (int i = 0; i < c; ++i) {
                const float u = c2[i];
                lt += (u < v) ? 1 : 0;
                le += (u <= v) ? 1 : 0;
            }
            if (ci < c) {
                if (lt <= q409 && q409 < le) s_d409[rl] = v;
                if (lt <= q410 && q410 < le) s_d410[rl] = v;
            }
        }
    }
    __syncthreads();

    // thresholds (exact jnp.quantile lerp, verified R2 path)
    if (t < RB * H_) {
        const int r = t >> 2, h = t & 3;
        const float scl = s_scale[h];
        const float s409 = __fmul_rn(s_d409[r], scl);
        const float s410 = __fmul_rn(s_d410[r], scl);
        const float pos = 0.2f * 2047.0f;
        const float g = pos - 409.0f;
        const float lw = 1.0f - g;
        s_th[r][h] = __fadd_rn(__fmul_rn(s409, lw), __fmul_rn(s410, g));
    }
    __syncthreads();

    // ---- phase 2 (R12-verified verbatim): K-tiled bf16 A-build + MFMA, mesh in LDS
    const int mr   = t >> 4;
    const int h_b  = mr >> 3;
    const int r_b  = mr & 7;
    const int jg   = t & 15;
    const int row16 = ((h_b & 1) << 3) + r_b;
    const int pln   = h_b >> 1;
    const float2 me_b = s_mesh[n0 + r_b];
    const float sc_b = s_scale[h_b];
    const float th_b = s_th[r_b][h_b];
    // A write offset with XOR bank swizzle: chunkSw = chunk ^ (ks4q & 7)
    const int ks4q_w = jg >> 1;
    const int chunk_w = ks4q_w * 16 + row16;
    const int chunkSw_w = chunk_w ^ (ks4q_w & 7);
    const int aoff = pln * APS + (chunkSw_w << 4) + ((jg & 1) << 3);
    float wacc = 0.0f;

    const int p_w  = w >> 2;
    const int ks_w = (w >> 1) & 1;
    const int nqh  = w & 1;
    const int ks4q_r = ks_w * 4 + (l >> 4);
    const int chunk_r = ks4q_r * 16 + (l & 15);
    const int aroff = p_w * APS + ((chunk_r ^ (ks4q_r & 7)) << 4);
    f32x4 acc[2];
    acc[0] = (f32x4)0.0f; acc[1] = (f32x4)0.0f;

    const float* inpb = inputs + (size_t)b * L_ * D_;
    const char* wsb = ws + (size_t)b * (L_ * D_ * 2);
    char* Abase = s_u1;                 // 2 planes x APS = 4128 B
    char* Bbase = s_u1 + 2 * APS;       // 8192 B

    #pragma unroll 1
    for (int tile = 0; tile < NTILE; ++tile) {
        __syncthreads();
        // B stage: pre-converted bf16 chunk from ws (1 uint4 per thread)
        const uint4 bg = *reinterpret_cast<const uint4*>(wsb + ((size_t)(tile * 512 + t) << 4));
        // A-build: 4 consecutive j per thread for fixed (r_b, h_b)
        const int k0 = tile * KT;
        {
            const float4 mq0 = *reinterpret_cast<const float4*>(&s_mesh[k0 + jg * 4]);
            const float4 mq1 = *reinterpret_cast<const float4*>(&s_mesh[k0 + jg * 4 + 2]);
            const float dx0 = __fsub_rn(me_b.x, mq0.x);
            const float dy0 = __fsub_rn(me_b.y, mq0.y);
            const float d0 = __fadd_rn(__fmul_rn(dx0, dx0), __fmul_rn(dy0, dy0));
            const float dx1 = __fsub_rn(me_b.x, mq0.z);
            const float dy1 = __fsub_rn(me_b.y, mq0.w);
            const float d1 = __fadd_rn(__fmul_rn(dx1, dx1), __fmul_rn(dy1, dy1));
            const float dx2 = __fsub_rn(me_b.x, mq1.x);
            const float dy2 = __fsub_rn(me_b.y, mq1.y);
            const float d2 = __fadd_rn(__fmul_rn(dx2, dx2), __fmul_rn(dy2, dy2));
            const float dx3 = __fsub_rn(me_b.x, mq1.z);
            const float dy3 = __fsub_rn(me_b.y, mq1.w);
            const float d3 = __fadd_rn(__fmul_rn(dx3, dx3), __fmul_rn(dy3, dy3));
            const float x0 = __fmul_rn(d0, sc_b);
            const float x1 = __fmul_rn(d1, sc_b);
            const float x2 = __fmul_rn(d2, sc_b);
            const float x3 = __fmul_rn(d3, sc_b);
            const float w0 = (x0 <= th_b) ? __expf(-x0) : 0.0f;
            const float w1 = (x1 <= th_b) ? __expf(-x1) : 0.0f;
            const float w2 = (x2 <= th_b) ? __expf(-x2) : 0.0f;
            const float w3 = (x3 <= th_b) ? __expf(-x3) : 0.0f;
            wacc += (w0 + w1) + (w2 + w3);
            const unsigned u01 = bf16_rne(w0) | (bf16_rne(w1) << 16);
            const unsigned u23 = bf16_rne(w2) | (bf16_rne(w3) << 16);
            *reinterpret_cast<uint2*>(Abase + aoff) = make_uint2(u01, u23);
        }
        // commit B to LDS
        *reinterpret_cast<uint4*>(Bbase + t * 16) = bg;
        __syncthreads();
        // MFMA: wave handles plane p_w, k-step ks_w, col-quads nqh*2, nqh*2+1
        const bf16x8 afr = *reinterpret_cast<const bf16x8*>(Abase + aroff);
        #pragma unroll
        for (int i = 0; i < 2; ++i) {
            const int nq = nqh * 2 + i;
            const bf16x8 bfr = *reinterpret_cast<const bf16x8*>(
                Bbase + (((ks_w * 4 + (l >> 4)) * 64 + nq * 16 + (l & 15)) << 4));
            acc[i] = __builtin_amdgcn_mfma_f32_16x16x32_bf16(afr, bfr, acc[i], 0, 0, 0);
        }
    }
    __syncthreads();

    // wsum: reduce over jg lanes, unique writer
    wacc += __shfl_xor(wacc, 1);
    wacc += __shfl_xor(wacc, 2);
    wacc += __shfl_xor(wacc, 4);
    wacc += __shfl_xor(wacc, 8);
    if ((l & 15) == 0) s_wsum[r_b][h_b] = wacc;
    // zero C region (8 KB)
    {
        float4* Cz = reinterpret_cast<float4*>(s_u1);
        Cz[t] = make_float4(0.f, 0.f, 0.f, 0.f);
    }
    __syncthreads();
    // reduce k-split accumulator frags into C[32][64]
    {
        float* Cf = reinterpret_cast<float*>(s_u1);
        #pragma unroll
        for (int i = 0; i < 2; ++i) {
            const int nq = nqh * 2 + i;
            #pragma unroll
            for (int reg = 0; reg < 4; ++reg) {
                const int row = (l >> 4) * 4 + reg;
                const int col = nq * 16 + (l & 15);
                atomicAdd(&Cf[(p_w * 16 + row) * 64 + col], acc[i][reg]);
            }
        }
    }
    __syncthreads();
    // normalize + store conv block
    {
        const float* Cf = reinterpret_cast<const float*>(s_u1);
        const int pr = t >> 4;                  // 0..31
        const int p = pr >> 4;
        const int row16o = pr & 15;
        const int h = p * 2 + (row16o >> 3);
        const int r = row16o & 7;
        const int col = (t & 15) << 2;
        const float wsv = s_wsum[r][h];
        const float inv = (wsv != 0.0f) ? 1.0f / wsv : 0.0f;
        float4 r0 = *reinterpret_cast<const float4*>(&Cf[pr * 64 + col]);
        r0.x *= inv; r0.y *= inv; r0.z *= inv; r0.w *= inv;
        float* op = out + (size_t)(b * L_ + n0 + r) * OUTW + D_ + h * 64 + col;
        *reinterpret_cast<float4*>(op) = r0;
    }
    // exact fp32 passthrough of inputs into out[:, :, 0:64]
    {
        const int r = t >> 6;                   // 0..7
        const int c = t & 63;
        out[(size_t)(b * L_ + n0 + r) * OUTW + c] = inpb[(size_t)(n0 + r) * D_ + c];
    }
}

extern "C" void kernel_launch(void* const* d_in, const int* in_sizes, int n_in,
                              void* d_out, int out_size, void* d_ws, size_t ws_size,
                              hipStream_t stream) {
    const float* mesh   = (const float*)d_in[0];
    const float* inputs = (const float*)d_in[1];
    const float* lmda   = (const float*)d_in[2];
    float* out = (float*)d_out;
    char* ws = (char*)d_ws;
    (void)in_sizes; (void)n_in; (void)out_size; (void)ws_size;
    hipLaunchKernelGGL(prep_kernel, dim3(256), dim3(256), 0, stream, inputs, ws);
    hipLaunchKernelGGL(posatt_kernel, dim3(B_ * (L_ / RB)), dim3(512), 0, stream,
                       mesh, inputs, lmda, ws, out);
}